// Round 8
// baseline (410.891 us; speedup 1.0000x reference)
//
#include <hip/hip_runtime.h>
#include <cstdint>
#include <cstddef>

// SelfAttention: B=8, S=2048, D=512, fp32 in/out.
// R8: flash restructured for register fit: 256 thr/block, 32 q-rows.
// Phase A waves=(key-half,q-half): sacc=16 regs. Phase C waves=d-quarter:
// acc=64 regs. S shared via LDS Pb; m/l/alpha state in LDS. ~130 regs/wave
// (<170 cap @ 3 waves/EU), LDS ~50.5KB -> 3 blocks/CU. No spills.
// proj z==2 writes V transposed directly (vtrans kernel deleted).
// ws: [qh 16M][kh 16M][vt 16M][xh 16M][Wt 1.5M] = 65.5 MiB.

#define SEQ 2048
#define DIM 512
#define NB 8
#define BSZ (NB * SEQ)

typedef __attribute__((ext_vector_type(8))) _Float16 half8;
typedef __attribute__((ext_vector_type(4))) float f32x4;

__device__ __forceinline__ unsigned short f2h(float f) {
  _Float16 h = (_Float16)f;
  return __builtin_bit_cast(unsigned short, h);
}
__device__ __forceinline__ half8 ld_frag(const unsigned short* p) {
  return *(const half8*)(const void*)p;
}
__device__ __forceinline__ void gl_lds16(const unsigned short* g, unsigned short* l) {
  __builtin_amdgcn_global_load_lds(
      (__attribute__((address_space(1))) void*)g,
      (__attribute__((address_space(3))) void*)l, 16, 0, 0);
}

// ---------------------------------------------------------------------------
__global__ __launch_bounds__(256) void cvt_x_kernel(
    const float* __restrict__ X, unsigned short* __restrict__ xh)
{
  size_t i0 = ((size_t)blockIdx.x * 256 + threadIdx.x) * 8;
  float4 a = *(const float4*)&X[i0];
  float4 b = *(const float4*)&X[i0 + 4];
  ushort4 o0; o0.x = f2h(a.x); o0.y = f2h(a.y); o0.z = f2h(a.z); o0.w = f2h(a.w);
  ushort4 o1; o1.x = f2h(b.x); o1.y = f2h(b.y); o1.z = f2h(b.z); o1.w = f2h(b.w);
  *(ushort4*)&xh[i0] = o0;
  *(ushort4*)&xh[i0 + 4] = o1;
}

// ---------------------------------------------------------------------------
__global__ __launch_bounds__(256) void cvt_w_kernel(
    const float* __restrict__ Wq, const float* __restrict__ Wk,
    const float* __restrict__ Wv, unsigned short* __restrict__ Wt)
{
  const int z = blockIdx.z;
  const float* W = (z == 0) ? Wq : (z == 1) ? Wk : Wv;
  unsigned short* out = Wt + (size_t)z * DIM * DIM;
  const int k0 = blockIdx.x * 64, n0 = blockIdx.y * 64;
  const int t = threadIdx.x;
  __shared__ unsigned short tl[64 * 72];
#pragma unroll
  for (int i = 0; i < 4; i++) {
    int f = t + 256 * i;
    int kr = f >> 4, c4 = (f & 15) * 4;
    float4 v = *(const float4*)&W[(size_t)(k0 + kr) * DIM + n0 + c4];
    tl[(c4 + 0) * 72 + kr] = f2h(v.x);
    tl[(c4 + 1) * 72 + kr] = f2h(v.y);
    tl[(c4 + 2) * 72 + kr] = f2h(v.z);
    tl[(c4 + 3) * 72 + kr] = f2h(v.w);
  }
  __syncthreads();
#pragma unroll
  for (int i = 0; i < 2; i++) {
    int f = t + 256 * i;
    int nr = f >> 3, k8 = (f & 7) * 8;
    *(uint4*)&out[(size_t)(n0 + nr) * DIM + k0 + k8] = *(const uint4*)&tl[nr * 72 + k8];
  }
}

// ---------------------------------------------------------------------------
// proj: q/k -> row-major fp16 (repacked coalesced store); v (z==2) -> scatter
// directly transposed into vt[b][d][s].
// ---------------------------------------------------------------------------
__global__ __launch_bounds__(256) void proj_kernel(
    const unsigned short* __restrict__ xh, const unsigned short* __restrict__ Wt,
    const float* __restrict__ bq, const float* __restrict__ bk,
    const float* __restrict__ bv, unsigned short* __restrict__ outbase,
    unsigned short* __restrict__ vt)
{
  const int z = blockIdx.z;
  const unsigned short* Wz = Wt + (size_t)z * DIM * DIM;
  const float* bias = (z == 0) ? bq : (z == 1) ? bk : bv;
  unsigned short* out = outbase + (size_t)z * BSZ * DIM;
  const int m0 = blockIdx.x * 128, n0 = blockIdx.y * 128;
  const int t = threadIdx.x, lane = t & 63, wave = t >> 6;
  const int wrow = (wave >> 1) * 64, wcol = (wave & 1) * 64;
  const int lr = lane & 15, lq = (lane >> 4) * 8, lq4 = lane >> 4;

  __shared__ unsigned short sm[128 * 132];
  unsigned short* As = sm;
  unsigned short* Bs = sm + 128 * 64;

  f32x4 acc[4][4];
  const f32x4 zero = {0.f, 0.f, 0.f, 0.f};
#pragma unroll
  for (int r = 0; r < 4; r++)
#pragma unroll
    for (int c = 0; c < 4; c++) acc[r][c] = zero;

  for (int k0 = 0; k0 < DIM; k0 += 64) {
    __syncthreads();
#pragma unroll
    for (int i = 0; i < 4; i++) {
      int f = t + 256 * i;
      int row = f >> 3, c8 = (f & 7) * 8;
      gl_lds16(&xh[(size_t)(m0 + row) * DIM + k0 + c8], &As[i * 2048 + wave * 512]);
      gl_lds16(&Wz[(size_t)(n0 + row) * DIM + k0 + c8], &Bs[i * 2048 + wave * 512]);
    }
    __syncthreads();
#pragma unroll
    for (int kk = 0; kk < 64; kk += 32) {
      half8 a[4], b[4];
#pragma unroll
      for (int r = 0; r < 4; r++) a[r] = ld_frag(&As[(wrow + 16 * r + lr) * 64 + kk + lq]);
#pragma unroll
      for (int c = 0; c < 4; c++) b[c] = ld_frag(&Bs[(wcol + 16 * c + lr) * 64 + kk + lq]);
#pragma unroll
      for (int r = 0; r < 4; r++)
#pragma unroll
        for (int c = 0; c < 4; c++)
          acc[r][c] = __builtin_amdgcn_mfma_f32_16x16x32_f16(a[r], b[c], acc[r][c], 0, 0, 0);
    }
  }

  if (z == 2) {
    // V: scatter transposed. global row s = m0+wrow+16r+lq4*4+e (e contiguous),
    // col d = n0+wcol+16c+lr. vt[b][d][s], b = m0>>11, s0 = m0&2047.
    const int b = m0 >> 11;
    const int s0 = m0 & 2047;
#pragma unroll
    for (int c = 0; c < 4; c++) {
      int col = n0 + wcol + 16 * c + lr;
      float bb = bias[col];
      unsigned short* vrow = vt + ((size_t)b * DIM + col) * SEQ;
#pragma unroll
      for (int r = 0; r < 4; r++) {
        int s = s0 + wrow + 16 * r + lq4 * 4;
        ushort4 pk;
        pk.x = f2h(acc[r][c][0] + bb);
        pk.y = f2h(acc[r][c][1] + bb);
        pk.z = f2h(acc[r][c][2] + bb);
        pk.w = f2h(acc[r][c][3] + bb);
        *(ushort4*)&vrow[s] = pk;
      }
    }
  } else {
    __syncthreads();
#pragma unroll
    for (int c = 0; c < 4; c++) {
      float bb = bias[n0 + wcol + 16 * c + lr];
#pragma unroll
      for (int r = 0; r < 4; r++)
#pragma unroll
        for (int e = 0; e < 4; e++)
          sm[(wrow + 16 * r + lq4 * 4 + e) * 132 + wcol + 16 * c + lr] =
              f2h(acc[r][c][e] + bb);
    }
    __syncthreads();
#pragma unroll
    for (int i = 0; i < 8; i++) {
      int f = t + 256 * i;
      int row = f >> 4, c8 = (f & 15) * 8;
      *(uint4*)&out[(size_t)(m0 + row) * DIM + n0 + c8] = *(const uint4*)&sm[row * 132 + c8];
    }
  }
}

// ---------------------------------------------------------------------------
// flash R8: 256 threads, 32 q-rows/block, 512 blocks.
// Phase A: wave=(kh,qh) computes S^T for 64 keys x 16 q (sacc[4]).
// Softmax: per-lane scalar state, cross-wave merge via LDS pml/psum.
// Phase C: wave=d-quarter (128 d), P^T B-frags shared from Pb LDS (acc[8][2]).
// xor-16 swizzle on K/Q staging; xor-(row^row>>2)&3 on V (32-half rows).
// ---------------------------------------------------------------------------
__global__ __launch_bounds__(256, 3) void flash_kernel(
    const unsigned short* __restrict__ Qb2, const unsigned short* __restrict__ Kb,
    const unsigned short* __restrict__ Vtb, float* __restrict__ Ob)
{
  const int zb = blockIdx.x & 7;          // batch -> XCD affinity
  const int q0 = (blockIdx.x >> 3) * 32;  // q-tile base row
  const unsigned short* Q = Qb2 + (size_t)zb * SEQ * DIM;
  const unsigned short* K = Kb + (size_t)zb * SEQ * DIM;
  const unsigned short* V = Vtb + (size_t)zb * DIM * SEQ;  // [d][s]
  float* Out = Ob + (size_t)zb * SEQ * DIM;

  const int t = threadIdx.x;
  const int lane = t & 63;
  const int wave = t >> 6;      // 0..3
  const int kh = wave >> 1;     // phase A: key half
  const int qh = wave & 1;      // phase A: q half
  const int lr = lane & 15, lq4 = lane >> 4;
  const float L2E = 1.4426950408889634f;

  __shared__ unsigned short KV[16384];   // 32KB: K[128][128] | V[512][32]
  __shared__ unsigned short Qs[4096];    // 8KB: Q[32][128]
  __shared__ unsigned short Pb[32 * 136];
  __shared__ float pml[2][32], psum[2][32], mstate[32], lstate[32], abuf[32];

  if (t < 32) { mstate[t] = -1e30f; lstate[t] = 0.f; }

  f32x4 acc[8][2];
  const f32x4 zero = {0.f, 0.f, 0.f, 0.f};
#pragma unroll
  for (int dd = 0; dd < 8; dd++) { acc[dd][0] = zero; acc[dd][1] = zero; }

  const int q = 16 * qh + lr;  // this lane's q-row in phases A/B

  for (int j = 0; j < 16; j++) {
    // ===== phase A: S^T tile (128 keys x 32 q), wave covers 64k x 16q =====
    f32x4 sacc[4];
#pragma unroll
    for (int c = 0; c < 4; c++) sacc[c] = zero;
#pragma unroll
    for (int dch = 0; dch < 4; dch++) {
      __syncthreads();
#pragma unroll
      for (int i = 0; i < 8; i++) {
        int f = t + 256 * i;
        int row = f >> 4, c16 = f & 15;
        int sc = c16 ^ (row & 15);
        gl_lds16(&K[(size_t)(j * 128 + row) * DIM + dch * 128 + sc * 8],
                 &KV[i * 2048 + wave * 512]);
      }
#pragma unroll
      for (int i = 0; i < 2; i++) {
        int f = t + 256 * i;
        int row = f >> 4, c16 = f & 15;
        int sc = c16 ^ (row & 15);
        gl_lds16(&Q[(size_t)(q0 + row) * DIM + dch * 128 + sc * 8],
                 &Qs[i * 2048 + wave * 512]);
      }
      __syncthreads();
#pragma unroll
      for (int ks2 = 0; ks2 < 4; ks2++) {
        half8 qf = ld_frag(&Qs[(16 * qh + lr) * 128 + (((ks2 << 2) + lq4) ^ lr) * 8]);
#pragma unroll
        for (int c = 0; c < 4; c++) {
          half8 kf = ld_frag(
              &KV[(64 * kh + 16 * c + lr) * 128 + (((ks2 << 2) + lq4) ^ lr) * 8]);
          sacc[c] = __builtin_amdgcn_mfma_f32_16x16x32_f16(kf, qf, sacc[c], 0, 0, 0);
        }
      }
    }

    // ===== phase B: online softmax =====
    float mx = sacc[0][0];
#pragma unroll
    for (int c = 0; c < 4; c++)
#pragma unroll
      for (int e = 0; e < 4; e++) mx = fmaxf(mx, sacc[c][e]);
    mx = fmaxf(mx, __shfl_xor(mx, 16, 64));
    mx = fmaxf(mx, __shfl_xor(mx, 32, 64));
    if (lq4 == 0) pml[kh][q] = mx;
    __syncthreads();  // B1: pml ready (also protects KV reads, last use above)

    float mnew = fmaxf(mstate[q], fmaxf(pml[0][q], pml[1][q]));
    float sum = 0.f;
#pragma unroll
    for (int c = 0; c < 4; c++) {
      float p0 = exp2f((sacc[c][0] - mnew) * L2E);
      float p1 = exp2f((sacc[c][1] - mnew) * L2E);
      float p2 = exp2f((sacc[c][2] - mnew) * L2E);
      float p3 = exp2f((sacc[c][3] - mnew) * L2E);
      sum += (p0 + p1) + (p2 + p3);
      ushort4 pk;
      pk.x = f2h(p0); pk.y = f2h(p1); pk.z = f2h(p2); pk.w = f2h(p3);
      *(ushort4*)&Pb[q * 136 + 64 * kh + 16 * c + lq4 * 4] = pk;
    }
    sum += __shfl_xor(sum, 16, 64);
    sum += __shfl_xor(sum, 32, 64);
    if (lq4 == 0) psum[kh][q] = sum;
    __syncthreads();  // B2: Pb + psum complete

    if (t < 32) {
      float mo = mstate[t];
      float mn = fmaxf(mo, fmaxf(pml[0][t], pml[1][t]));
      float a = exp2f((mo - mn) * L2E);
      lstate[t] = a * lstate[t] + psum[0][t] + psum[1][t];
      mstate[t] = mn;
      abuf[t] = a;
    }
    __syncthreads();  // B3: state published

    float a0 = abuf[lr], a1 = abuf[16 + lr];
#pragma unroll
    for (int dd = 0; dd < 8; dd++) {
      acc[dd][0][0] *= a0; acc[dd][0][1] *= a0; acc[dd][0][2] *= a0; acc[dd][0][3] *= a0;
      acc[dd][1][0] *= a1; acc[dd][1][1] *= a1; acc[dd][1][2] *= a1; acc[dd][1][3] *= a1;
    }

    // ===== phase C: O^T += V^T P^T; wave owns d in [128*wave, +128) =====
#pragma unroll
    for (int kc = 0; kc < 4; kc++) {
      __syncthreads();
#pragma unroll
      for (int i = 0; i < 8; i++) {
        int f = t + 256 * i;
        int row = f >> 2, c4 = f & 3;
        int sc = c4 ^ ((row ^ (row >> 2)) & 3);
        gl_lds16(&V[(size_t)row * SEQ + j * 128 + kc * 32 + sc * 8],
                 &KV[i * 2048 + wave * 512]);
      }
      __syncthreads();
      half8 pf0 = ld_frag(&Pb[(lr) * 136 + kc * 32 + lq4 * 8]);
      half8 pf1 = ld_frag(&Pb[(16 + lr) * 136 + kc * 32 + lq4 * 8]);
#pragma unroll
      for (int dd = 0; dd < 8; dd++) {
        int row = 128 * wave + 16 * dd + lr;
        int sc = lq4 ^ ((row ^ (row >> 2)) & 3);
        half8 vf = ld_frag(&KV[row * 32 + sc * 8]);
        acc[dd][0] = __builtin_amdgcn_mfma_f32_16x16x32_f16(vf, pf0, acc[dd][0], 0, 0, 0);
        acc[dd][1] = __builtin_amdgcn_mfma_f32_16x16x32_f16(vf, pf1, acc[dd][1], 0, 0, 0);
      }
    }
  }

  // ===== epilogue: O[q][d] = acc / l  (64B-contiguous segments per quarter)
  float inv0 = 1.0f / lstate[lr];
  float inv1 = 1.0f / lstate[16 + lr];
#pragma unroll
  for (int dd = 0; dd < 8; dd++) {
    int d = 128 * wave + 16 * dd + lq4 * 4;
    float4 w0, w1;
    w0.x = acc[dd][0][0] * inv0; w0.y = acc[dd][0][1] * inv0;
    w0.z = acc[dd][0][2] * inv0; w0.w = acc[dd][0][3] * inv0;
    w1.x = acc[dd][1][0] * inv1; w1.y = acc[dd][1][1] * inv1;
    w1.z = acc[dd][1][2] * inv1; w1.w = acc[dd][1][3] * inv1;
    *(float4*)&Out[(size_t)(q0 + lr) * DIM + d] = w0;
    *(float4*)&Out[(size_t)(q0 + 16 + lr) * DIM + d] = w1;
  }
}

// ---------------------------------------------------------------------------
extern "C" void kernel_launch(void* const* d_in, const int* in_sizes, int n_in,
                              void* d_out, int out_size, void* d_ws, size_t ws_size,
                              hipStream_t stream)
{
  const float* X  = (const float*)d_in[0];
  const float* Wq = (const float*)d_in[1];
  const float* bq = (const float*)d_in[2];
  const float* Wk = (const float*)d_in[3];
  const float* bk = (const float*)d_in[4];
  const float* Wv = (const float*)d_in[5];
  const float* bv = (const float*)d_in[6];
  float* Out = (float*)d_out;

  char* ws = (char*)d_ws;
  const size_t MB = 1u << 20;
  unsigned short* qh = (unsigned short*)(ws);            // 16 MiB
  unsigned short* kh = (unsigned short*)(ws + 16 * MB);  // 16 MiB (proj z=1)
  unsigned short* vt = (unsigned short*)(ws + 32 * MB);  // 16 MiB (proj z=2 direct)
  unsigned short* xh = (unsigned short*)(ws + 48 * MB);  // 16 MiB
  unsigned short* Wt = (unsigned short*)(ws + 64 * MB);  // 1.5 MiB

  cvt_x_kernel<<<dim3(BSZ * DIM / 2048), 256, 0, stream>>>(X, xh);
  cvt_w_kernel<<<dim3(8, 8, 3), 256, 0, stream>>>(Wq, Wk, Wv, Wt);
  proj_kernel<<<dim3(BSZ / 128, DIM / 128, 3), 256, 0, stream>>>(
      xh, Wt, bq, bk, bv, qh, vt);
  flash_kernel<<<dim3(NB * SEQ / 32), 256, 0, stream>>>(qh, kh, vt, Out);
}